// Round 3
// baseline (107.101 us; speedup 1.0000x reference)
//
#include <hip/hip_runtime.h>
#include <math.h>

// HiPPO-LegS reconstruction: out = sum_{k=1..256} coef[k-1]*sqrt(2k+1)*P_k(x),
// x = 2t/curr_t - 1.
//
// Model (fit R1-R8): dur_us = harness floor (268MB ws re-poison fill @ ~41us,
// 82% HBM peak, + replay overhead; floor drifts ~5us across sessions/containers)
// + kernel. Kernel VALU floor: 512 FMA-ops/pt x 524288 pts / (1024 SIMD x 32
// lane x 2.4GHz) = 3.41us. Clenshaw at 2 ops/degree is op-minimal among fp32-
// viable schemes (monomial Horner overflows: P_256 coeffs > 2^500; even/odd
// x^2-split needs 3 ops/deg; no packed-f32 on gfx950).
//
// R9 (A/B vs R8; R10 = retry, GPU acquisition timed out in R9's round):
// R8 ran 2 waves/SIMD (4pt/thread, 512 blocks) -- prologue (cold 900cy
// t-load + LDS setup + barrier) and ds_read bursts have only 2-deep TLP to
// hide under. R9: 2pt/thread, 1024 blocks = 4 blocks/CU = 4 waves/SIMD.
// Same VALU floor; DS demand 1024 reads/CU x ~6cy = 6.1K cyc < 8192-cyc
// VALU window (sub-critical). If this lands within ~2us of R8's 68.7,
// both are at the kernel floor and dur_us is harness-dominated -> roofline.
//
//   Clenshaw on rescaled basis S_{d+1} = 2x*S_d - beta_d*S_{d-1}:
//   b_k = w'_k + 2x*b_{k+1} - beta_{k+1}*b_{k+2};  f = x*b_1 - (2/3)*b_2
//   beta_d = 4d^2/(4d^2-1) (compile-time), w'_k = coef[k-1]*sqrt(2k+1)*g_k

#define NDEG 256

// g_i = 2*C(2i,i)/4^i: exact for i<8, 4-term Stirling beyond (rel < 1e-7).
__device__ __forceinline__ float g_of(int i) {
    const float fi = (float)i;
    float r = 2.0f * rsqrtf(3.14159265358979f * fi);
    float inv = 1.0f / fi;
    float corr = 1.0f + inv * (-0.125f + inv * (0.0078125f + inv * 0.0048828125f));
    float g = r * corr;
    g = (i == 1) ? 1.0f          : g;
    g = (i == 2) ? 0.75f         : g;
    g = (i == 3) ? 0.625f        : g;
    g = (i == 4) ? 0.546875f     : g;
    g = (i == 5) ? 0.4921875f    : g;
    g = (i == 6) ? 0.451171875f  : g;
    g = (i == 7) ? 0.4189453125f : g;
    return g;
}

// -beta_{d} as a compile-time-foldable constant.
constexpr float nbeta(int d) {
    double dd = (double)d;
    return (float)(-(4.0 * dd * dd) / (4.0 * dd * dd - 1.0));
}

// One Clenshaw degree for 2 independent points. nb lands in an SGPR (one
// s_mov, co-issued) so t_p = fma(nb,b2_p,w) is VOP3 v_fma; n_p = fma(U,b1,t)
// is VOP2 v_fmac. 4 FMAs with 2-way ILP; b-renames vanish under full unroll.
__device__ __forceinline__ void step2(
    const float U0, const float U1,
    float& b10, float& b20, float& b11, float& b21,
    const float nb, const float w)
{
    float t0 = fmaf(nb, b20, w);
    float t1 = fmaf(nb, b21, w);
    float n0 = fmaf(U0, b10, t0);
    float n1 = fmaf(U1, b11, t1);
    b20 = b10; b21 = b11;
    b10 = n0;  b11 = n1;
}

#define STEP2(NB, W) step2(U0, U1, b10, b20, b11, b21, (NB), (W))

__global__ __launch_bounds__(256, 4) void hippo_kernel(
    const float* __restrict__ t,
    const float* __restrict__ coef,
    const int* __restrict__ curr_t,
    float* __restrict__ out,
    int n)
{
    // w'[k], k=1..256: w4[j] = {w'(4j+1), w'(4j+2), w'(4j+3), w'(4j+4)}
    __shared__ float4 w4[NDEG / 4];
    float* wf = (float*)w4;

    const int tid = threadIdx.x;
    {
        const int k = tid + 1;
        wf[tid] = coef[tid] * sqrtf(2.0f * (float)k + 1.0f) * g_of(k);
    }
    __syncthreads();

    const int gid  = blockIdx.x * 256 + tid;  // float2-group index
    const int base = gid * 2;
    const float s = 2.0f / (float)curr_t[0];

    float2 tv;
    if (base + 1 < n) {
        tv = reinterpret_cast<const float2*>(t)[gid];
    } else {  // tail safety (never taken at n=524288)
        tv.x = (base + 0 < n) ? t[base + 0] : 0.0f;
        tv.y = 0.0f;
    }

    const float x0 = fmaf(tv.x, s, -1.0f);
    const float x1 = fmaf(tv.y, s, -1.0f);
    const float U0 = 2.0f * x0;
    const float U1 = 2.0f * x1;

    float b10 = 0.0f, b20 = 0.0f;   // b_258 = b_257 = 0, per point
    float b11 = 0.0f, b21 = 0.0f;

#pragma unroll
    for (int j = 63; j >= 0; --j) {
        const float4 c = w4[j];   // broadcast ds_read_b128, 1 per 4 degrees
        STEP2(nbeta(4 * j + 5), c.w);  // degree 4j+4
        STEP2(nbeta(4 * j + 4), c.z);  // degree 4j+3
        STEP2(nbeta(4 * j + 3), c.y);  // degree 4j+2
        STEP2(nbeta(4 * j + 2), c.x);  // degree 4j+1
    }

    // f = x*b_1 - beta_1*S_0*b_2 = x*b1 - (4/3)*(1/2)*b2
    float2 ov;
    ov.x = fmaf(x0, b10, -0.66666666666667f * b20);
    ov.y = fmaf(x1, b11, -0.66666666666667f * b21);

    if (base + 1 < n) {
        reinterpret_cast<float2*>(out)[gid] = ov;
    } else if (base < n) {
        out[base] = ov.x;
    }
}

extern "C" void kernel_launch(void* const* d_in, const int* in_sizes, int n_in,
                              void* d_out, int out_size, void* d_ws, size_t ws_size,
                              hipStream_t stream)
{
    const float* t      = (const float*)d_in[0];
    const float* coef   = (const float*)d_in[1];
    const int*   curr_t = (const int*)d_in[2];
    float*       out    = (float*)d_out;

    int n = in_sizes[0];                   // 524288
    int blocks = (n + 511) / 512;          // 1024 blocks = 4 blocks/CU, 4 waves/SIMD
    hippo_kernel<<<blocks, 256, 0, stream>>>(t, coef, curr_t, out, n);
}

// Round 4
// 63.634 us; speedup vs baseline: 1.6831x; 1.6831x over previous
//
#include <hip/hip_runtime.h>
#include <math.h>

// HiPPO-LegS reconstruction: out = sum_{k=1..256} coef[k-1]*sqrt(2k+1)*P_k(x),
// x = 2t/curr_t - 1.
//
// Model (fit over R1-R9): dur_us = harness floor (268MB ws re-poison fill
// @ ~41us, 82% HBM peak, drifts +-5us across containers) + kernel.
// Kernel VALU floor: 512 FMA/pt = ~3.4us; this kernel (R7) measured ~5.4us.
//
// R9 POST-MORTEM (do not repeat): __launch_bounds__(256,4) halves the VGPR
// cap to 128; under full unroll the scheduler hoists the 64 ds_read_b128s,
// and at cap 128 it SPILLS the hoist window to scratch instead of shortening
// it: 146 MiB writes + 72 MiB reads per dispatch (584 B/thread = ~36 float4
// slots), kernel 50us memory-bound at 4.5 TB/s. VALUBusy 12.6%. The cap-64
// config below ((256,8)) is proven to keep the window tight with NO spill
// (kernel ~5.4us, invisible in top-5). Remaining in-kernel headroom (~2us to
// the 2-op/degree Clenshaw issue floor) is below harness floor drift (+-5us),
// so this is the risk-optimal anchor.
//
//   Clenshaw on rescaled basis S_{d+1} = 2x*S_d - beta_d*S_{d-1}:
//   b_k = w'_k + 2x*b_{k+1} - beta_{k+1}*b_{k+2};  f = x*b_1 - (2/3)*b_2
//   beta_d = 4d^2/(4d^2-1) (compile-time), w'_k = coef[k-1]*sqrt(2k+1)*g_k

#define NDEG 256

// g_i = 2*C(2i,i)/4^i: exact for i<8, 4-term Stirling beyond (rel < 1e-7).
__device__ __forceinline__ float g_of(int i) {
    const float fi = (float)i;
    float r = 2.0f * rsqrtf(3.14159265358979f * fi);
    float inv = 1.0f / fi;
    float corr = 1.0f + inv * (-0.125f + inv * (0.0078125f + inv * 0.0048828125f));
    float g = r * corr;
    g = (i == 1) ? 1.0f          : g;
    g = (i == 2) ? 0.75f         : g;
    g = (i == 3) ? 0.625f        : g;
    g = (i == 4) ? 0.546875f     : g;
    g = (i == 5) ? 0.4921875f    : g;
    g = (i == 6) ? 0.451171875f  : g;
    g = (i == 7) ? 0.4189453125f : g;
    return g;
}

// -beta_{d} as a compile-time-foldable constant.
constexpr float nbeta(int d) {
    double dd = (double)d;
    return (float)(-(4.0 * dd * dd) / (4.0 * dd * dd - 1.0));
}

// One Clenshaw degree: b_K = w + 2x*b1 - beta_{K+1}*b2.
// Shaped so both ops are v_fmac_f32 (VOP2, literal nb inline in src0).
__device__ __forceinline__ void step(const float U, float& b1, float& b2,
                                     const float nb, const float w) {
    float tt = fmaf(nb, b2, w);   // v_fmac: tt(=w) += nb*b2
    float bn = fmaf(U, b1, tt);   // v_fmac: tt += U*b1
    b2 = b1;
    b1 = bn;
}

__global__ __launch_bounds__(256, 8) void hippo_kernel(
    const float* __restrict__ t,
    const float* __restrict__ coef,
    const int* __restrict__ curr_t,
    float* __restrict__ out,
    int n)
{
    // w'[k], k=1..256: w4[j] = {w'(4j+1), w'(4j+2), w'(4j+3), w'(4j+4)}
    __shared__ float4 w4[NDEG / 4];
    float* wf = (float*)w4;

    const int tid = threadIdx.x;
    {
        const int k = tid + 1;
        wf[tid] = coef[tid] * sqrtf(2.0f * (float)k + 1.0f) * g_of(k);
    }
    __syncthreads();

    const int gid = blockIdx.x * 256 + tid;
    const float s = 2.0f / (float)curr_t[0];
    const float x = fmaf(t[gid < n ? gid : 0], s, -1.0f);  // x = 2t/curr_t - 1
    const float U = 2.0f * x;

    float b1 = 0.0f, b2 = 0.0f;   // b_258 = b_257 = 0
#pragma unroll
    for (int j = 63; j >= 0; --j) {
        const float4 c = w4[j];   // broadcast ds_read_b128, scheduler-managed
        step(U, b1, b2, nbeta(4 * j + 5), c.w);  // degree 4j+4
        step(U, b1, b2, nbeta(4 * j + 4), c.z);  // degree 4j+3
        step(U, b1, b2, nbeta(4 * j + 3), c.y);  // degree 4j+2
        step(U, b1, b2, nbeta(4 * j + 2), c.x);  // degree 4j+1
    }

    // f = x*b_1 - beta_1*S_0*b_2 = x*b1 - (4/3)*(1/2)*b2
    if (gid < n)
        out[gid] = fmaf(x, b1, -0.66666666666667f * b2);
}

extern "C" void kernel_launch(void* const* d_in, const int* in_sizes, int n_in,
                              void* d_out, int out_size, void* d_ws, size_t ws_size,
                              hipStream_t stream)
{
    const float* t      = (const float*)d_in[0];
    const float* coef   = (const float*)d_in[1];
    const int*   curr_t = (const int*)d_in[2];
    float*       out    = (float*)d_out;

    int n = in_sizes[0];                 // 524288
    int blocks = (n + 255) / 256;        // 2048 blocks -> 8 waves/SIMD
    hippo_kernel<<<blocks, 256, 0, stream>>>(t, coef, curr_t, out, n);
}